// Round 6
// baseline (687.960 us; speedup 1.0000x reference)
//
#include <hip/hip_runtime.h>

// UniversalGRU: 2-layer GRU (B=2048, T=512, D=1, H=64) + FC(64->1).
// R6: wave-autonomous pipeline, ZERO barriers in the t-loop.
// 256 blocks x 256 threads (4 waves). Wave wv: (layer = wv>>1 ? 1 : 0,
// row-group g = wv&1, rows 4g..4g+3). Each wave owns the FULL 64-col
// recurrence of its 4 rows: MFMA M16(4 real)xN192, preacts round-trip
// wave-private LDS (per-wave in-order DS pipe -> no sync), gates 4/lane
// (lane = col, rows 0..3), h stays in registers. L0->L1 handoff via a
// depth-2 LDS ring + seq/ack flags (slack 2) instead of __syncthreads.

#define T_LEN 512

typedef float          f32x4 __attribute__((ext_vector_type(4)));
typedef __bf16         bf16x8 __attribute__((ext_vector_type(8)));
typedef unsigned short us8   __attribute__((ext_vector_type(8)));
typedef unsigned short ushort_t;

__device__ __forceinline__ float bf2f(ushort_t b){
    unsigned int u = ((unsigned int)b) << 16;
    return __uint_as_float(u);
}
__device__ __forceinline__ ushort_t f2bf(float f){
    unsigned int u = __float_as_uint(f);
    u = (u + 0x7FFFu + ((u >> 16) & 1u)) >> 16;   // RNE
    return (ushort_t)u;
}
__device__ __forceinline__ float ld_any(const void* p, int i, bool f32){
    return f32 ? ((const float*)p)[i] : bf2f(((const ushort_t*)p)[i]);
}
__device__ __forceinline__ float sigm(float x){
    float e = __expf(-x);
    return __fdividef(1.0f, 1.0f + e);
}
__device__ __forceinline__ float tanh_f(float x){
    float e = __expf(2.0f * x);
    return fmaf(-2.0f, __fdividef(1.0f, e + 1.0f), 1.0f);
}
__device__ __forceinline__ f32x4 mfma16(bf16x8 a, bf16x8 b, f32x4 c){
    return __builtin_amdgcn_mfma_f32_16x16x32_bf16(a, b, c, 0, 0, 0);
}
// B-fragment: 8 contiguous k's of W[n][k] (n = output col), either dtype.
__device__ __forceinline__ bf16x8 mk_frag(const void* W, int n, int kb, bool f32){
    us8 tmp;
    #pragma unroll
    for (int j = 0; j < 8; ++j){
        tmp[j] = f32 ? f2bf(((const float*)W)[n * 64 + kb + j])
                     : ((const ushort_t*)W)[n * 64 + kb + j];
    }
    return __builtin_bit_cast(bf16x8, tmp);
}
#define SCHED_FENCE() __builtin_amdgcn_sched_barrier(0)

__global__ __launch_bounds__(256, 1) void gru_fused(
    const void* __restrict__ xv,
    const void* __restrict__ Wih0, const void* __restrict__ Whh0,
    const void* __restrict__ bih0, const void* __restrict__ bhh0,
    const void* __restrict__ Wih1, const void* __restrict__ Whh1,
    const void* __restrict__ bih1, const void* __restrict__ bhh1,
    const void* __restrict__ Wfc,  const void* __restrict__ bfc,
    void* __restrict__ outv)
{
    __shared__ float    xbuf[8 * T_LEN];                 // staged x, f32, flat
    __shared__ ushort_t ringA[2][2][16 * 72];            // [group][slot] hA, A-layout
    __shared__ ushort_t hbB[2][16 * 72];                 // [group] hB (L1-wave-private)
    __shared__ __align__(16) float P[4][4][64][4];       // [wave][gate][col][row] preacts
    __shared__ float    outb[8][68];
    __shared__ int      flg[8];                          // [0..1]=seqA, [2..3]=ackA

    const int tid  = threadIdx.x;
    const int wv   = tid >> 6;                // 0..3
    const int lane = tid & 63;                // = gate col
    const int g    = wv & 1;                  // row-group (rows 4g..4g+3)
    const bool isL1 = (wv >= 2);
    const int c    = lane & 15;
    const int q    = lane >> 4;
    const int aoff = c * 72 + q * 8;          // A-frag: A[m=c][k=8q(+32f)]
    const long row0 = (long)blockIdx.x * 8;

    // dtype detect (uniform): fp32 misread as bf16 -> mantissa-noise exponents.
    bool f32 = false;
    {
        const ushort_t* xs = (const ushort_t*)xv;
        for (int j = 0; j < 64; ++j){
            int e = (xs[2 * j] >> 7) & 0xFF;
            if (e > 150) f32 = true;
        }
    }

    // zero rings / flags
    for (int k = tid; k < 2 * 2 * 16 * 72; k += 256) ((ushort_t*)ringA)[k] = 0;
    for (int k = tid; k < 2 * 16 * 72;     k += 256) ((ushort_t*)hbB)[k]   = 0;
    if (tid < 8) flg[tid] = 0;
    // stage x: 8 rows x 512 -> f32 flat
    if (f32){
        const float* xf = (const float*)xv + row0 * T_LEN;
        #pragma unroll
        for (int i = 0; i < 4; ++i){
            f32x4 v = ((const f32x4*)xf)[tid + 256 * i];
            *(f32x4*)&xbuf[(tid + 256 * i) * 4] = v;
        }
    } else {
        const ushort_t* xs = (const ushort_t*)xv + row0 * T_LEN;
        #pragma unroll
        for (int i = 0; i < 2; ++i){
            us8 v = ((const us8*)xs)[tid + 256 * i];
            #pragma unroll
            for (int j = 0; j < 8; ++j) xbuf[(tid + 256 * i) * 8 + j] = bf2f(v[j]);
        }
    }
    __syncthreads();

    volatile int* seqA = (volatile int*)&flg[0];
    volatile int* ackA = (volatile int*)&flg[2];
    float hreg[4] = {0.f, 0.f, 0.f, 0.f};     // h for (rows 0..3 of group, col=lane)

    if (!isL1){
        // ---------------- layer-0 wave ----------------
        bf16x8 wr[4][2], wz[4][2], wn[4][2];  // Whh0 B-frags, n = gate*64+16j+c
        #pragma unroll
        for (int j = 0; j < 4; ++j){
            #pragma unroll
            for (int f = 0; f < 2; ++f){
                const int kb = f * 32 + q * 8;
                wr[j][f] = mk_frag(Whh0,       16 * j + c, kb, f32);
                wz[j][f] = mk_frag(Whh0,  64 + 16 * j + c, kb, f32);
                wn[j][f] = mk_frag(Whh0, 128 + 16 * j + c, kb, f32);
            }
        }
        const float w0r = ld_any(Wih0, lane, f32);
        const float w0z = ld_any(Wih0, 64 + lane, f32);
        const float w0n = ld_any(Wih0, 128 + lane, f32);
        const float b0r  = ld_any(bih0, lane, f32)      + ld_any(bhh0, lane, f32);
        const float b0z  = ld_any(bih0, 64 + lane, f32) + ld_any(bhh0, 64 + lane, f32);
        const float b0nx = ld_any(bih0, 128 + lane, f32);
        const float b0nh = ld_any(bhh0, 128 + lane, f32);

        for (int t = 0; t < T_LEN; ++t){
            const ushort_t* rs = ringA[g][(t + 1) & 1];   // hA(t-1), own writes
            us8 a0u = *(const us8*)&rs[aoff];
            us8 a1u = *(const us8*)&rs[aoff + 32];
            bf16x8 a0 = __builtin_bit_cast(bf16x8, a0u);
            bf16x8 a1 = __builtin_bit_cast(bf16x8, a1u);
            f32x4 R[4], Z[4], N[4];
            #pragma unroll
            for (int j = 0; j < 4; ++j){
                R[j] = (f32x4){0.f,0.f,0.f,0.f};
                Z[j] = (f32x4){0.f,0.f,0.f,0.f};
                N[j] = (f32x4){0.f,0.f,0.f,0.f};
            }
            #pragma unroll
            for (int j = 0; j < 4; ++j){
                R[j] = mfma16(a0, wr[j][0], R[j]); R[j] = mfma16(a1, wr[j][1], R[j]);
                Z[j] = mfma16(a0, wz[j][0], Z[j]); Z[j] = mfma16(a1, wz[j][1], Z[j]);
                N[j] = mfma16(a0, wn[j][0], N[j]); N[j] = mfma16(a1, wn[j][1], N[j]);
            }
            if (lane < 16){
                #pragma unroll
                for (int j = 0; j < 4; ++j){
                    *(f32x4*)&P[wv][0][16 * j + c][0] = R[j];
                    *(f32x4*)&P[wv][1][16 * j + c][0] = Z[j];
                    *(f32x4*)&P[wv][2][16 * j + c][0] = N[j];
                }
            }
            SCHED_FENCE();                       // in-order DS: writes precede reads
            f32x4 pR = *(const f32x4*)&P[wv][0][lane][0];
            f32x4 pZ = *(const f32x4*)&P[wv][1][lane][0];
            f32x4 pN = *(const f32x4*)&P[wv][2][lane][0];
            float xm[4];
            #pragma unroll
            for (int r = 0; r < 4; ++r) xm[r] = xbuf[(g * 4 + r) * T_LEN + t];
            while (ackA[g] < t - 1) {}           // anti-dep: L1 done with hA(t-2)
            SCHED_FENCE();
            ushort_t* ws = ringA[g][t & 1];
            #pragma unroll
            for (int r = 0; r < 4; ++r){
                float rg = sigm(pR[r] + fmaf(xm[r], w0r, b0r));
                float zg = sigm(pZ[r] + fmaf(xm[r], w0z, b0z));
                float ng = tanh_f(fmaf(xm[r], w0n, b0nx) + rg * (pN[r] + b0nh));
                hreg[r] = ng + zg * (hreg[r] - ng);
                ws[r * 72 + lane] = f2bf(hreg[r]);
            }
            SCHED_FENCE();                       // data writes precede flag publish
            if (lane == 0) seqA[g] = t + 1;
        }
    } else {
        // ---------------- layer-1 wave ----------------
        bf16x8 wir[4][2], wiz[4][2], win[4][2];  // Wih1
        bf16x8 whr[4][2], whz[4][2], whn[4][2];  // Whh1
        #pragma unroll
        for (int j = 0; j < 4; ++j){
            #pragma unroll
            for (int f = 0; f < 2; ++f){
                const int kb = f * 32 + q * 8;
                wir[j][f] = mk_frag(Wih1,       16 * j + c, kb, f32);
                wiz[j][f] = mk_frag(Wih1,  64 + 16 * j + c, kb, f32);
                win[j][f] = mk_frag(Wih1, 128 + 16 * j + c, kb, f32);
                whr[j][f] = mk_frag(Whh1,       16 * j + c, kb, f32);
                whz[j][f] = mk_frag(Whh1,  64 + 16 * j + c, kb, f32);
                whn[j][f] = mk_frag(Whh1, 128 + 16 * j + c, kb, f32);
            }
        }
        const float b1r  = ld_any(bih1, lane, f32)      + ld_any(bhh1, lane, f32);
        const float b1z  = ld_any(bih1, 64 + lane, f32) + ld_any(bhh1, 64 + lane, f32);
        const float b1nx = ld_any(bih1, 128 + lane, f32);
        const float b1nh = ld_any(bhh1, 128 + lane, f32);

        for (int t = 0; t < T_LEN; ++t){
            while (seqA[g] < t + 1) {}           // wait hA(t) published
            SCHED_FENCE();
            const ushort_t* ra = ringA[g][t & 1];
            us8 ha0u = *(const us8*)&ra[aoff];
            us8 ha1u = *(const us8*)&ra[aoff + 32];
            us8 hb0u = *(const us8*)&hbB[g][aoff];       // own hB(t-1)
            us8 hb1u = *(const us8*)&hbB[g][aoff + 32];
            SCHED_FENCE();                       // reads in pipe before ack
            if (lane == 0) ackA[g] = t + 1;
            bf16x8 ha0 = __builtin_bit_cast(bf16x8, ha0u);
            bf16x8 ha1 = __builtin_bit_cast(bf16x8, ha1u);
            bf16x8 hb0 = __builtin_bit_cast(bf16x8, hb0u);
            bf16x8 hb1 = __builtin_bit_cast(bf16x8, hb1u);
            f32x4 R[4], Z[4], XN[4], HN[4];
            #pragma unroll
            for (int j = 0; j < 4; ++j){
                R[j]  = (f32x4){0.f,0.f,0.f,0.f};
                Z[j]  = (f32x4){0.f,0.f,0.f,0.f};
                XN[j] = (f32x4){0.f,0.f,0.f,0.f};
                HN[j] = (f32x4){0.f,0.f,0.f,0.f};
            }
            #pragma unroll
            for (int j = 0; j < 4; ++j){
                R[j]  = mfma16(ha0, wir[j][0], R[j]);  R[j]  = mfma16(ha1, wir[j][1], R[j]);
                R[j]  = mfma16(hb0, whr[j][0], R[j]);  R[j]  = mfma16(hb1, whr[j][1], R[j]);
                Z[j]  = mfma16(ha0, wiz[j][0], Z[j]);  Z[j]  = mfma16(ha1, wiz[j][1], Z[j]);
                Z[j]  = mfma16(hb0, whz[j][0], Z[j]);  Z[j]  = mfma16(hb1, whz[j][1], Z[j]);
                XN[j] = mfma16(ha0, win[j][0], XN[j]); XN[j] = mfma16(ha1, win[j][1], XN[j]);
                HN[j] = mfma16(hb0, whn[j][0], HN[j]); HN[j] = mfma16(hb1, whn[j][1], HN[j]);
            }
            if (lane < 16){
                #pragma unroll
                for (int j = 0; j < 4; ++j){
                    *(f32x4*)&P[wv][0][16 * j + c][0] = R[j];
                    *(f32x4*)&P[wv][1][16 * j + c][0] = Z[j];
                    *(f32x4*)&P[wv][2][16 * j + c][0] = XN[j];
                    *(f32x4*)&P[wv][3][16 * j + c][0] = HN[j];
                }
            }
            SCHED_FENCE();
            f32x4 pR  = *(const f32x4*)&P[wv][0][lane][0];
            f32x4 pZ  = *(const f32x4*)&P[wv][1][lane][0];
            f32x4 pXN = *(const f32x4*)&P[wv][2][lane][0];
            f32x4 pHN = *(const f32x4*)&P[wv][3][lane][0];
            ushort_t* wsb = hbB[g];
            #pragma unroll
            for (int r = 0; r < 4; ++r){
                float rg = sigm(pR[r] + b1r);
                float zg = sigm(pZ[r] + b1z);
                float ng = tanh_f(pXN[r] + b1nx + rg * (pHN[r] + b1nh));
                hreg[r] = ng + zg * (hreg[r] - ng);
                wsb[r * 72 + lane] = f2bf(hreg[r]);   // reads of hB(t-1) already in pipe
            }
        }
        #pragma unroll
        for (int r = 0; r < 4; ++r) outb[g * 4 + r][lane] = hreg[r];
    }
    __syncthreads();

    // FC: out[row] = sum_i Wfc[i]*h2[row][i] + bfc
    if (tid < 8){
        float s = ld_any(bfc, 0, f32);
        for (int i2 = 0; i2 < 64; ++i2) s = fmaf(ld_any(Wfc, i2, f32), outb[tid][i2], s);
        if (f32) ((float*)outv)[row0 + tid] = s;
        else     ((ushort_t*)outv)[row0 + tid] = f2bf(s);
    }
}

extern "C" void kernel_launch(void* const* d_in, const int* in_sizes, int n_in,
                              void* d_out, int out_size, void* d_ws, size_t ws_size,
                              hipStream_t stream)
{
    (void)in_sizes; (void)n_in; (void)d_ws; (void)ws_size;
    const int B = out_size;            // O = 1 -> out_size == batch
    const int nblk = B / 8;            // 2048/8 = 256 blocks, 1 per CU
    gru_fused<<<nblk, 256, 0, stream>>>(
        d_in[0],
        d_in[1], d_in[2], d_in[3], d_in[4],
        d_in[5], d_in[6], d_in[7], d_in[8],
        d_in[9], d_in[10],
        d_out);
}

// Round 7
// 455.813 us; speedup vs baseline: 1.5093x; 1.5093x over previous
//
#include <hip/hip_runtime.h>
#include <hip/hip_fp16.h>

// UniversalGRU: 2-layer GRU (B=2048, T=512, D=1, H=64) + FC(64->1).
// R7 = R4 structure (layer-skewed, 1 barrier/t, 256 blocks x 512 thr) with
// DS-pipe traffic cut ~45%: preact redistribution packs the 2 shuffled rows
// into one f16x2 word -> ONE ds_bpermute per gate value (L0 8->3, L1 16->4),
// and L0's x-terms are added post-shuffle (xm reads 4->2 per lane).
// Rationale: LDS is CU-shared (~6 cyc/wave-op); R4 issued ~990 DS bank-cyc
// per CU per timestep -- the dominant cost. Waves 0-3 = L0 step t,
// waves 4-7 = L1 step t-1 (both need only hA(t-1), hB(t-2)).

#define T_LEN 512
#define ROWS  8
#define XPAD  513

typedef float          f32x4 __attribute__((ext_vector_type(4)));
typedef __bf16         bf16x8 __attribute__((ext_vector_type(8)));
typedef unsigned short us8   __attribute__((ext_vector_type(8)));
typedef unsigned short ushort_t;

__device__ __forceinline__ float bf2f(ushort_t b){
    unsigned int u = ((unsigned int)b) << 16;
    return __uint_as_float(u);
}
__device__ __forceinline__ ushort_t f2bf(float f){
    unsigned int u = __float_as_uint(f);
    u = (u + 0x7FFFu + ((u >> 16) & 1u)) >> 16;   // RNE
    return (ushort_t)u;
}
__device__ __forceinline__ float ld_any(const void* p, int i, bool f32){
    return f32 ? ((const float*)p)[i] : bf2f(((const ushort_t*)p)[i]);
}
__device__ __forceinline__ float sigm(float x){
    float e = __expf(-x);
    return __fdividef(1.0f, 1.0f + e);
}
__device__ __forceinline__ float tanh_f(float x){
    float e = __expf(2.0f * x);
    return fmaf(-2.0f, __fdividef(1.0f, e + 1.0f), 1.0f);
}
__device__ __forceinline__ f32x4 mfma16(bf16x8 a, bf16x8 b, f32x4 c){
    return __builtin_amdgcn_mfma_f32_16x16x32_bf16(a, b, c, 0, 0, 0);
}
// f16x2 pack/unpack for single-shfl redistribution of two preact rows.
__device__ __forceinline__ float pack2(float a, float b){
    __half2 h = __floats2half2_rn(a, b);          // v_cvt_pkrtz
    return __builtin_bit_cast(float, h);
}
__device__ __forceinline__ float2 unpack2(float p){
    __half2 h = __builtin_bit_cast(__half2, p);
    return __half22float2(h);
}
// Build a B-fragment (8 contiguous k's of W[n][k]) from either dtype.
__device__ __forceinline__ bf16x8 mk_frag(const void* W, int n, int kb, bool f32){
    us8 tmp;
    #pragma unroll
    for (int j = 0; j < 8; ++j){
        tmp[j] = f32 ? f2bf(((const float*)W)[n * 64 + kb + j])
                     : ((const ushort_t*)W)[n * 64 + kb + j];
    }
    return __builtin_bit_cast(bf16x8, tmp);
}

__global__ __launch_bounds__(512, 2) void gru_fused(
    const void* __restrict__ xv,
    const void* __restrict__ Wih0, const void* __restrict__ Whh0,
    const void* __restrict__ bih0, const void* __restrict__ bhh0,
    const void* __restrict__ Wih1, const void* __restrict__ Whh1,
    const void* __restrict__ bih1, const void* __restrict__ bhh1,
    const void* __restrict__ Wfc,  const void* __restrict__ bfc,
    void* __restrict__ outv)
{
    __shared__ float    xbuf[ROWS * XPAD];       // staged x, padded stride
    __shared__ ushort_t hbufA[2][16 * 72];       // layer-0 h, A-layout bf16, dbuf
    __shared__ ushort_t hbufB[2][16 * 72];       // layer-1 h
    __shared__ float    outb[ROWS][68];          // final h2 for FC

    const int tid  = threadIdx.x;
    const int wv   = tid >> 6;                   // 0..7
    const bool isL1 = (wv >= 4);
    const int w    = wv & 3;                     // n-tile group within role
    const int c    = tid & 15;                   // MFMA col-within-tile
    const int q    = (tid >> 4) & 3;             // quad
    const int ih   = w * 16 + c;                 // h-col this lane's gates own
    const int hi   = q >> 1;                     // upper-half-wave flag
    const int mrow = (q & 1) * 4 + hi * 2;       // first of this lane's 2 REAL rows
    const long row0 = (long)blockIdx.x * ROWS;

    // dtype detection (uniform): fp32 misread as bf16 -> mantissa-noise
    // exponents in even ushort slots; true bf16 never exceeds exp 150.
    bool f32 = false;
    {
        const ushort_t* xs = (const ushort_t*)xv;
        for (int j = 0; j < 64; ++j){
            int e = (xs[2 * j] >> 7) & 0xFF;
            if (e > 150) f32 = true;
        }
    }

    // zero h double-buffers (h0 = 0; also hB(-1)=0 for the skewed start)
    {
        ushort_t* pa = &hbufA[0][0];
        ushort_t* pb = &hbufB[0][0];
        for (int k = tid; k < 2 * 16 * 72; k += 512){ pa[k] = 0; pb[k] = 0; }
    }
    // stage x: wave wv loads row wv (8 rows x 512), coalesced
    {
        const int r = wv;
        const int g = tid & 63;
        if (f32){
            const f32x4* src = (const f32x4*)((const float*)xv + (row0 + r) * T_LEN);
            #pragma unroll
            for (int it = 0; it < 2; ++it){
                f32x4 v = src[g + 64 * it];
                #pragma unroll
                for (int j = 0; j < 4; ++j)
                    xbuf[r * XPAD + (g + 64 * it) * 4 + j] = v[j];
            }
        } else {
            const us8* src = (const us8*)((const ushort_t*)xv + (row0 + r) * T_LEN);
            us8 v = src[g];
            #pragma unroll
            for (int j = 0; j < 8; ++j)
                xbuf[r * XPAD + g * 8 + j] = bf2f(v[j]);
        }
    }

    // Role-specific weights. B[k][n]=W[n][k]; lane: n = 64*g + ih, k = 32*f+8*q+j.
    bf16x8 wA[3][2], wB[3][2];                   // L0: wA=Whh0. L1: wA=Wih1, wB=Whh1.
    float sxr = 0.f, sxz = 0.f, sxn = 0.f;       // L0 scalar x-weights
    float br, bz, bnx, bnh;
    if (!isL1){
        #pragma unroll
        for (int g = 0; g < 3; ++g){
            const int n = g * 64 + ih;
            #pragma unroll
            for (int f = 0; f < 2; ++f)
                wA[g][f] = mk_frag(Whh0, n, f * 32 + q * 8, f32);
        }
        sxr = ld_any(Wih0, ih, f32);
        sxz = ld_any(Wih0, 64 + ih, f32);
        sxn = ld_any(Wih0, 128 + ih, f32);
        br  = ld_any(bih0, ih, f32)       + ld_any(bhh0, ih, f32);
        bz  = ld_any(bih0, 64 + ih, f32)  + ld_any(bhh0, 64 + ih, f32);
        bnx = ld_any(bih0, 128 + ih, f32);
        bnh = ld_any(bhh0, 128 + ih, f32);
    } else {
        #pragma unroll
        for (int g = 0; g < 3; ++g){
            const int n = g * 64 + ih;
            #pragma unroll
            for (int f = 0; f < 2; ++f){
                wA[g][f] = mk_frag(Wih1, n, f * 32 + q * 8, f32);
                wB[g][f] = mk_frag(Whh1, n, f * 32 + q * 8, f32);
            }
        }
        br  = ld_any(bih1, ih, f32)       + ld_any(bhh1, ih, f32);
        bz  = ld_any(bih1, 64 + ih, f32)  + ld_any(bhh1, 64 + ih, f32);
        bnx = ld_any(bih1, 128 + ih, f32);
        bnh = ld_any(bhh1, 128 + ih, f32);
    }

    float h2[2] = {0.f, 0.f};          // fp32-carried h for this lane's 2 real rows
    const int aoff = c * 72 + q * 8;   // A-frag base: A[m=c][k=8q(+32f)]

    __syncthreads();

    for (int t = 0; t < T_LEN; ++t){
        const int p = t & 1;
        if (!isL1){
            // ---- layer 0, step t: hA(t) = GRU0(x(t), hA(t-1))
            us8 a0u = *(const us8*)&hbufA[p][aoff];
            us8 a1u = *(const us8*)&hbufA[p][aoff + 32];
            bf16x8 a0 = __builtin_bit_cast(bf16x8, a0u);
            bf16x8 a1 = __builtin_bit_cast(bf16x8, a1u);
            f32x4 aR = {br, br, br, br};
            f32x4 aZ = {bz, bz, bz, bz};
            f32x4 aN = {bnh, bnh, bnh, bnh};
            aR = mfma16(a0, wA[0][0], aR); aR = mfma16(a1, wA[0][1], aR);
            aZ = mfma16(a0, wA[1][0], aZ); aZ = mfma16(a1, wA[1][1], aZ);
            aN = mfma16(a0, wA[2][0], aN); aN = mfma16(a1, wA[2][1], aN);
            // single-shfl redistribution: regs(2,3) packed f16x2 -> lanes+32
            float2 uR = unpack2(__shfl_up(pack2(aR[2], aR[3]), 32));
            float2 uZ = unpack2(__shfl_up(pack2(aZ[2], aZ[3]), 32));
            float2 uN = unpack2(__shfl_up(pack2(aN[2], aN[3]), 32));
            float gR[2] = { hi ? uR.x : aR[0], hi ? uR.y : aR[1] };
            float gZ[2] = { hi ? uZ.x : aZ[0], hi ? uZ.y : aZ[1] };
            float gN[2] = { hi ? uN.x : aN[0], hi ? uN.y : aN[1] };
            float xm[2] = { xbuf[mrow * XPAD + t], xbuf[(mrow + 1) * XPAD + t] };
            #pragma unroll
            for (int j = 0; j < 2; ++j){
                float rg = sigm(fmaf(xm[j], sxr, gR[j]));
                float zg = sigm(fmaf(xm[j], sxz, gZ[j]));
                float ng = tanh_f(fmaf(xm[j], sxn, bnx) + rg * gN[j]);
                h2[j] = ng + zg * (h2[j] - ng);
                hbufA[p ^ 1][(mrow + j) * 72 + ih] = f2bf(h2[j]);
            }
        } else if (t > 0){
            // ---- layer 1, step t-1: hB(t-1) = GRU1(hA(t-1), hB(t-2))
            us8 a0u = *(const us8*)&hbufA[p][aoff];        // hA(t-1)
            us8 a1u = *(const us8*)&hbufA[p][aoff + 32];
            us8 b0u = *(const us8*)&hbufB[p][aoff];        // hB(t-2)
            us8 b1u = *(const us8*)&hbufB[p][aoff + 32];
            bf16x8 a0 = __builtin_bit_cast(bf16x8, a0u);
            bf16x8 a1 = __builtin_bit_cast(bf16x8, a1u);
            bf16x8 b0 = __builtin_bit_cast(bf16x8, b0u);
            bf16x8 b1 = __builtin_bit_cast(bf16x8, b1u);
            f32x4 aR  = {br, br, br, br};
            f32x4 aZ  = {bz, bz, bz, bz};
            f32x4 aXn = {bnx, bnx, bnx, bnx};
            f32x4 aHn = {bnh, bnh, bnh, bnh};
            aR  = mfma16(a0, wA[0][0], aR);  aR  = mfma16(a1, wA[0][1], aR);
            aR  = mfma16(b0, wB[0][0], aR);  aR  = mfma16(b1, wB[0][1], aR);
            aZ  = mfma16(a0, wA[1][0], aZ);  aZ  = mfma16(a1, wA[1][1], aZ);
            aZ  = mfma16(b0, wB[1][0], aZ);  aZ  = mfma16(b1, wB[1][1], aZ);
            aXn = mfma16(a0, wA[2][0], aXn); aXn = mfma16(a1, wA[2][1], aXn);
            aHn = mfma16(b0, wB[2][0], aHn); aHn = mfma16(b1, wB[2][1], aHn);
            float2 uR = unpack2(__shfl_up(pack2(aR[2],  aR[3]),  32));
            float2 uZ = unpack2(__shfl_up(pack2(aZ[2],  aZ[3]),  32));
            float2 uX = unpack2(__shfl_up(pack2(aXn[2], aXn[3]), 32));
            float2 uN = unpack2(__shfl_up(pack2(aHn[2], aHn[3]), 32));
            float gR[2] = { hi ? uR.x : aR[0],  hi ? uR.y : aR[1] };
            float gZ[2] = { hi ? uZ.x : aZ[0],  hi ? uZ.y : aZ[1] };
            float gX[2] = { hi ? uX.x : aXn[0], hi ? uX.y : aXn[1] };
            float gN[2] = { hi ? uN.x : aHn[0], hi ? uN.y : aHn[1] };
            #pragma unroll
            for (int j = 0; j < 2; ++j){
                float rg = sigm(gR[j]);
                float zg = sigm(gZ[j]);
                float ng = tanh_f(gX[j] + rg * gN[j]);
                h2[j] = ng + zg * (h2[j] - ng);
                hbufB[p ^ 1][(mrow + j) * 72 + ih] = f2bf(h2[j]);
            }
        }
        __syncthreads();
    }

    // Epilogue: L1 waves compute the final step hB(511) from hA(511), hB(510)
    // (both sit in buffer 0 after 512 iterations).
    if (isL1){
        us8 a0u = *(const us8*)&hbufA[0][aoff];
        us8 a1u = *(const us8*)&hbufA[0][aoff + 32];
        us8 b0u = *(const us8*)&hbufB[0][aoff];
        us8 b1u = *(const us8*)&hbufB[0][aoff + 32];
        bf16x8 a0 = __builtin_bit_cast(bf16x8, a0u);
        bf16x8 a1 = __builtin_bit_cast(bf16x8, a1u);
        bf16x8 b0 = __builtin_bit_cast(bf16x8, b0u);
        bf16x8 b1 = __builtin_bit_cast(bf16x8, b1u);
        f32x4 aR  = {br, br, br, br};
        f32x4 aZ  = {bz, bz, bz, bz};
        f32x4 aXn = {bnx, bnx, bnx, bnx};
        f32x4 aHn = {bnh, bnh, bnh, bnh};
        aR  = mfma16(a0, wA[0][0], aR);  aR  = mfma16(a1, wA[0][1], aR);
        aR  = mfma16(b0, wB[0][0], aR);  aR  = mfma16(b1, wB[0][1], aR);
        aZ  = mfma16(a0, wA[1][0], aZ);  aZ  = mfma16(a1, wA[1][1], aZ);
        aZ  = mfma16(b0, wB[1][0], aZ);  aZ  = mfma16(b1, wB[1][1], aZ);
        aXn = mfma16(a0, wA[2][0], aXn); aXn = mfma16(a1, wA[2][1], aXn);
        aHn = mfma16(b0, wB[2][0], aHn); aHn = mfma16(b1, wB[2][1], aHn);
        float2 uR = unpack2(__shfl_up(pack2(aR[2],  aR[3]),  32));
        float2 uZ = unpack2(__shfl_up(pack2(aZ[2],  aZ[3]),  32));
        float2 uX = unpack2(__shfl_up(pack2(aXn[2], aXn[3]), 32));
        float2 uN = unpack2(__shfl_up(pack2(aHn[2], aHn[3]), 32));
        float gR[2] = { hi ? uR.x : aR[0],  hi ? uR.y : aR[1] };
        float gZ[2] = { hi ? uZ.x : aZ[0],  hi ? uZ.y : aZ[1] };
        float gX[2] = { hi ? uX.x : aXn[0], hi ? uX.y : aXn[1] };
        float gN[2] = { hi ? uN.x : aHn[0], hi ? uN.y : aHn[1] };
        #pragma unroll
        for (int j = 0; j < 2; ++j){
            float rg = sigm(gR[j]);
            float zg = sigm(gZ[j]);
            float ng = tanh_f(gX[j] + rg * gN[j]);
            float hf = ng + zg * (h2[j] - ng);
            outb[mrow + j][ih] = hf;
        }
    }
    __syncthreads();

    // FC: out[row] = sum_i Wfc[i]*h2[row][i] + bfc
    if (tid < ROWS){
        float s = ld_any(bfc, 0, f32);
        for (int i2 = 0; i2 < 64; ++i2) s = fmaf(ld_any(Wfc, i2, f32), outb[tid][i2], s);
        if (f32) ((float*)outv)[row0 + tid] = s;
        else     ((ushort_t*)outv)[row0 + tid] = f2bf(s);
    }
}

extern "C" void kernel_launch(void* const* d_in, const int* in_sizes, int n_in,
                              void* d_out, int out_size, void* d_ws, size_t ws_size,
                              hipStream_t stream)
{
    (void)in_sizes; (void)n_in; (void)d_ws; (void)ws_size;
    const int B = out_size;            // O = 1 -> out_size == batch
    const int nblk = B / ROWS;         // 2048/8 = 256 blocks
    gru_fused<<<nblk, 512, 0, stream>>>(
        d_in[0],
        d_in[1], d_in[2], d_in[3], d_in[4],
        d_in[5], d_in[6], d_in[7], d_in[8],
        d_in[9], d_in[10],
        d_out);
}